// Round 1
// baseline (509.879 us; speedup 1.0000x reference)
//
#include <hip/hip_runtime.h>
#include <math.h>

#define BLOCK 256
#define N_MOD 8
#define NEG_INF (-__builtin_inff())

__global__ __launch_bounds__(BLOCK) void wta_kernel(
    const float* __restrict__ x,
    const int*   __restrict__ mask,
    const float* __restrict__ W,
    float*       __restrict__ out,
    int B)
{
    // --- per-block softmax(W) into LDS (8 values, broadcast-read later) ---
    __shared__ float sw[N_MOD];
    if (threadIdx.x == 0) {
        float w[N_MOD];
        float m = NEG_INF;
        #pragma unroll
        for (int j = 0; j < N_MOD; ++j) { w[j] = W[j]; m = fmaxf(m, w[j]); }
        float s = 0.0f;
        #pragma unroll
        for (int j = 0; j < N_MOD; ++j) { w[j] = expf(w[j] - m); s += w[j]; }
        float inv = 1.0f / s;
        #pragma unroll
        for (int j = 0; j < N_MOD; ++j) sw[j] = w[j] * inv;
    }
    __syncthreads();

    int b = blockIdx.x * BLOCK + threadIdx.x;
    if (b >= B) return;

    // --- coalesced vector loads: 32B x + 32B mask per row ---
    const float4* xv = (const float4*)(x + (size_t)b * N_MOD);
    float4 xa = xv[0];
    float4 xb = xv[1];
    const int4* mv = (const int4*)(mask + (size_t)b * N_MOD);
    int4 ma = mv[0];
    int4 mb = mv[1];

    float v[N_MOD];
    v[0] = ma.x ? xa.x : NEG_INF;
    v[1] = ma.y ? xa.y : NEG_INF;
    v[2] = ma.z ? xa.z : NEG_INF;
    v[3] = ma.w ? xa.w : NEG_INF;
    v[4] = mb.x ? xb.x : NEG_INF;
    v[5] = mb.y ? xb.y : NEG_INF;
    v[6] = mb.z ? xb.z : NEG_INF;
    v[7] = mb.w ? xb.w : NEG_INF;

    // --- top-2 scan; strict '>' preserves lax.top_k lower-index-first ties ---
    float best1 = NEG_INF, best2 = NEG_INF;
    int i1 = 0, i2 = 0;
    #pragma unroll
    for (int j = 0; j < N_MOD; ++j) {
        float vj = v[j];
        if (vj > best1) {
            best2 = best1; i2 = i1;
            best1 = vj;   i1 = j;
        } else if (vj > best2) {
            best2 = vj;   i2 = j;
        }
    }

    // out = v1*softW[i1] + v2*softW[i2] + mean(v1, v2)
    out[b] = best1 * sw[i1] + best2 * sw[i2] + 0.5f * (best1 + best2);
}

extern "C" void kernel_launch(void* const* d_in, const int* in_sizes, int n_in,
                              void* d_out, int out_size, void* d_ws, size_t ws_size,
                              hipStream_t stream) {
    const float* x    = (const float*)d_in[0];
    const int*   mask = (const int*)d_in[1];
    const float* W    = (const float*)d_in[2];
    float*       out  = (float*)d_out;

    int B = out_size;  // 8388608 rows, one output per row
    int grid = (B + BLOCK - 1) / BLOCK;
    wta_kernel<<<grid, BLOCK, 0, stream>>>(x, mask, W, out, B);
}